// Round 14
// baseline (236.737 us; speedup 1.0000x reference)
//
#include <hip/hip_runtime.h>

namespace {
constexpr int NS   = 64;                 // batch
constexpr int NPS  = 802816;             // elements per sample (256*56*56)
constexpr int NPSV = NPS / 4;            // float4 per sample (200704)
constexpr unsigned KSEL = 80281u;        // int(0.1 * 802816)
constexpr unsigned SENT = 0xFFFFFFFFu;
constexpr int NB   = 8192;               // 13-bit prefix bins (u >> 18)
constexpr int GX   = 16;                 // scatter blocks per sample (interleaved tiles)
constexpr int TPB  = 49;                 // tiles per scatter block (784 = 16*49, no tail)
constexpr int PAIRCAP = 2048;            // candidate capacity per scatter block
constexpr int CAP_LDS = 20480;           // per-sample candidate cap for LDS select
constexpr int BRB  = 8;                  // bracket blocks per sample
constexpr int CHUNKS = 128;              // sampled 256-float4 chunks per sample
constexpr int CH_STRIDE = NPSV / CHUNKS; // 1568 float4 between chunk starts
// sample M = 131072 elems; mean rank of k-th = 13109, sigma = 108.6; +/-9 sigma
constexpr unsigned RU_RANK = 12129u;
constexpr unsigned RL_RANK = 14086u;
}

// Find bin B (descending) with suffix(B) < K <= suffix(B)+h[B]. SENT if total < K.
// Results are register-latched before the final barrier so back-to-back calls are safe.
template <int NBINS>
__device__ void select_in_lds(const unsigned* __restrict__ h, unsigned K,
                              unsigned* bin, unsigned* rem) {
    constexpr int BPT = NBINS / 256;
    __shared__ unsigned cs[256];
    __shared__ unsigned fB, fR;
    const int t = threadIdx.x;
    unsigned s = 0;
    for (int j = 0; j < BPT; ++j) s += h[t * BPT + j];
    cs[t] = s;
    if (t == 0) { fB = SENT; fR = 0u; }
    __syncthreads();
    unsigned suf = 0;
    for (int j = t + 1; j < 256; ++j) suf += cs[j];
    if (suf < K && suf + s >= K) {
        unsigned cur = suf;
        for (int j = BPT - 1; j >= 0; --j) {
            const unsigned c = h[t * BPT + j];
            if (cur < K && cur + c >= K) { fB = (unsigned)(t * BPT + j); fR = K - cur; break; }
            cur += c;
        }
    }
    __syncthreads();
    const unsigned rb = fB, rr = fR;
    __syncthreads();
    *bin = rb; *rem = rr;
}

// ---- bracket: chunk-sampled 13-bit histogram, 8 blocks/sample -> u16 partials ----
__global__ __launch_bounds__(256) void bracket_kernel(const float4* __restrict__ f,
                                                      const float4* __restrict__ g,
                                                      unsigned short* __restrict__ bh,
                                                      unsigned* __restrict__ fail) {
    __shared__ unsigned h[NB];
    const int jb = blockIdx.x, b = blockIdx.y, t = threadIdx.x;
    if (jb == 0 && b == 0 && t == 0) fail[0] = 0u;
    for (int k = t; k < NB; k += 256) h[k] = 0u;
    __syncthreads();
    const size_t base = (size_t)b * NPSV;
#define HBIN(p) { if ((p) > 0.0f) atomicAdd(&h[__float_as_uint(p) >> 18], 1u); }
    for (int c = 0; c < CHUNKS / BRB; c += 2) {          // 2-chunk unroll: 4 loads in flight
        const int ch = jb * (CHUNKS / BRB) + c;
        const size_t i0 = base + (size_t)ch * CH_STRIDE + t;
        const size_t i1 = base + (size_t)(ch + 1) * CH_STRIDE + t;
        const float4 fa = f[i0], fb = f[i1];
        const float4 ga = g[i0], gb = g[i1];
        HBIN(fa.x * ga.x) HBIN(fa.y * ga.y) HBIN(fa.z * ga.z) HBIN(fa.w * ga.w)
        HBIN(fb.x * gb.x) HBIN(fb.y * gb.y) HBIN(fb.z * gb.z) HBIN(fb.w * gb.w)
    }
#undef HBIN
    __syncthreads();
    unsigned short* o = bh + (size_t)(b * BRB + jb) * NB;
    for (int k = t; k < NB; k += 256) o[k] = (unsigned short)h[k];  // <=16384, fits u16
}

// ---- bracket_scan: dense uint4 reads — thread owns 8 consecutive bins, no atomics ----
__global__ __launch_bounds__(256) void bracket_scan_kernel(const unsigned short* __restrict__ bh,
                                                           unsigned* __restrict__ binLU) {
    __shared__ unsigned h[NB];
    const int b = blockIdx.x, t = threadIdx.x;
    for (int grp = t; grp < NB / 8; grp += 256) {        // 4 iterations
        unsigned acc[8] = {0, 0, 0, 0, 0, 0, 0, 0};
        for (int j = 0; j < BRB; ++j) {
            const uint4 v = *reinterpret_cast<const uint4*>(
                bh + (size_t)(b * BRB + j) * NB + grp * 8);   // 8 contiguous u16
            acc[0] += v.x & 0xFFFFu; acc[1] += v.x >> 16;
            acc[2] += v.y & 0xFFFFu; acc[3] += v.y >> 16;
            acc[4] += v.z & 0xFFFFu; acc[5] += v.z >> 16;
            acc[6] += v.w & 0xFFFFu; acc[7] += v.w >> 16;
        }
        for (int e = 0; e < 8; ++e) h[grp * 8 + e] = acc[e];
    }
    __syncthreads();
    unsigned bU, rU, bL, rL;
    select_in_lds<NB>(h, RU_RANK, &bU, &rU);
    select_in_lds<NB>(h, RL_RANK, &bL, &rL);
    if (t == 0) {
        binLU[2 * b]     = (bL == SENT) ? 0u : bL;
        binLU[2 * b + 1] = (bU == SENT) ? (unsigned)(NB - 1) : bU;
    }
}

// ---- scatter0: interleaved tile mapping, plain stores; candidate appends staged
//      in LDS, flushed coalesced at block end ----
__global__ __launch_bounds__(256) void scatter0_kernel(const float4* __restrict__ f,
                                                       const float4* __restrict__ g,
                                                       float4* __restrict__ out,
                                                       unsigned* __restrict__ pv,
                                                       unsigned* __restrict__ ppos,
                                                       const unsigned* __restrict__ binLU,
                                                       unsigned* __restrict__ cnts,
                                                       unsigned* __restrict__ chis,
                                                       unsigned* __restrict__ fail) {
    const int j = blockIdx.x, b = blockIdx.y, t = threadIdx.x;
    const unsigned binL = binLU[2 * b], binU = binLU[2 * b + 1];
    __shared__ unsigned cnt;
    __shared__ unsigned wsum[4];
    __shared__ unsigned lv[PAIRCAP];
    __shared__ unsigned lp[PAIRCAP];
    if (t == 0) cnt = 0u;
    __syncthreads();
    const size_t sbase = (size_t)b * NPSV;
    unsigned chi = 0;
#define PROC(FC, GC, IDX, CIDX, OC) { \
        const float p_ = (FC) * (GC); \
        const unsigned u_ = __float_as_uint(p_); \
        const unsigned pre_ = u_ >> 18; \
        const bool pos_ = p_ > 0.0f; \
        const bool drop_ = pos_ && (pre_ > binU); \
        OC = drop_ ? 0.0f : (FC); \
        chi += drop_; \
        if (pos_ && pre_ >= binL && pre_ <= binU) { \
            const unsigned x_ = atomicAdd(&cnt, 1u); \
            if (x_ < PAIRCAP) { lv[x_] = u_; lp[x_] = (unsigned)((IDX) * 4) + CIDX; } \
        } }
#define PROC4(FV, GV, IDX, OV) \
        PROC(FV.x, GV.x, IDX, 0u, OV.x) PROC(FV.y, GV.y, IDX, 1u, OV.y) \
        PROC(FV.z, GV.z, IDX, 2u, OV.z) PROC(FV.w, GV.w, IDX, 3u, OV.w)

    for (int k = 0; k < TPB; ++k) {
        const int i = (k * GX + j) * 256 + t;    // f4 index within sample
        const float4 fv = f[sbase + i];
        const float4 gv = g[sbase + i];
        float4 o;
        PROC4(fv, gv, i, o)
        out[sbase + i] = o;
    }
#undef PROC4
#undef PROC
    // block-reduce chi
    for (int off = 32; off; off >>= 1) chi += __shfl_down(chi, off);
    if ((t & 63) == 0) wsum[t >> 6] = chi;
    __syncthreads();
    // coalesced flush of the candidate staging
    const unsigned ctot = cnt;
    const unsigned c = (ctot > PAIRCAP) ? PAIRCAP : ctot;
    const size_t segp = (size_t)(b * GX + j) * PAIRCAP;
    for (unsigned k = t; k < c; k += 256) { pv[segp + k] = lv[k]; ppos[segp + k] = lp[k]; }
    if (t == 0) {
        chis[b * GX + j] = wsum[0] + wsum[1] + wsum[2] + wsum[3];
        cnts[b * GX + j] = c;
        if (ctot > PAIRCAP) fail[0] = 1u;   // overflow -> exact fallback
    }
}

// ---- select0+fixup: LDS-resident exact 3-level radix select, then zero the
//      candidate positions above the threshold (vals already in LDS) ----
__global__ __launch_bounds__(256) void select0_kernel(const unsigned* __restrict__ pv,
                                                      const unsigned* __restrict__ ppos,
                                                      const unsigned* __restrict__ binLU,
                                                      const unsigned* __restrict__ cnts,
                                                      const unsigned* __restrict__ chis,
                                                      unsigned* __restrict__ fail,
                                                      float* __restrict__ thrF,
                                                      float* __restrict__ out) {
    if (fail[0]) return;
    const int b = blockIdx.x, t = threadIdx.x;
    __shared__ unsigned vals[CAP_LDS];
    __shared__ unsigned hist[NB];
    __shared__ unsigned soff[GX + 1];
    __shared__ unsigned sh_chi;
    __shared__ float sh_thr;
    if (t == 0) {
        unsigned o = 0;
        for (int j = 0; j < GX; ++j) { soff[j] = o; o += cnts[b * GX + j]; }
        soff[GX] = o;
        unsigned c = 0;
        for (int j = 0; j < GX; ++j) c += chis[b * GX + j];
        sh_chi = c;
    }
    __syncthreads();
    const unsigned ncand = soff[GX];
    const unsigned chi = sh_chi;
    if (chi >= KSEL) { if (t == 0) fail[0] = 1u; return; }      // k-th above bracket
    if (ncand > CAP_LDS) { if (t == 0) fail[0] = 1u; return; }
    const unsigned Krem = KSEL - chi;
    bool zeroThr = false;
    if (Krem > ncand) {
        if (binLU[2 * b] == 0u) zeroThr = true;                 // < k positives: thr = 0
        else { if (t == 0) fail[0] = 1u; return; }              // k-th below bracket
    }
    // load candidates into LDS
    for (int j = 0; j < GX; ++j) {
        const unsigned c = soff[j + 1] - soff[j];
        const unsigned* s = pv + (size_t)(b * GX + j) * PAIRCAP;
        for (unsigned i = t; i < c; i += 256) vals[soff[j] + i] = s[i];
    }
    if (zeroThr) {
        if (t == 0) { sh_thr = 0.0f; thrF[b] = 0.0f; }
        __syncthreads();
    } else {
        // sweep 1: bits 30..18
        for (int k = t; k < NB; k += 256) hist[k] = 0u;
        __syncthreads();
        for (unsigned i = t; i < ncand; i += 256) atomicAdd(&hist[vals[i] >> 18], 1u);
        __syncthreads();
        unsigned P1, r1; select_in_lds<NB>(hist, Krem, &P1, &r1);
        __syncthreads();
        // sweep 2: bits 17..5
        for (int k = t; k < NB; k += 256) hist[k] = 0u;
        __syncthreads();
        for (unsigned i = t; i < ncand; i += 256) {
            const unsigned u = vals[i];
            if ((u >> 18) == P1) atomicAdd(&hist[(u >> 5) & (NB - 1u)], 1u);
        }
        __syncthreads();
        unsigned P2, r2; select_in_lds<NB>(hist, r1, &P2, &r2);
        __syncthreads();
        // sweep 3: bits 4..0
        if (t < 32) hist[t] = 0u;
        __syncthreads();
        const unsigned pref = (P1 << 13) | P2;
        for (unsigned i = t; i < ncand; i += 256) {
            const unsigned u = vals[i];
            if ((u >> 5) == pref) atomicAdd(&hist[u & 31u], 1u);
        }
        __syncthreads();
        if (t == 0) {
            unsigned cur = 0, b3 = 0;
            for (int q = 31; q >= 0; --q) {
                const unsigned c = hist[q];
                if (cur < r2 && cur + c >= r2) { b3 = (unsigned)q; break; }
                cur += c;
            }
            const float thr = __uint_as_float((P1 << 18) | (P2 << 5) | b3);
            sh_thr = thr; thrF[b] = thr;
        }
        __syncthreads();
    }
    // fixup: zero candidate positions whose value exceeds thr
    const float thr = sh_thr;
    float* ob = out + (size_t)b * NPS;
    for (int j = 0; j < GX; ++j) {
        const unsigned c = soff[j + 1] - soff[j];
        const unsigned* qp = ppos + (size_t)(b * GX + j) * PAIRCAP;
        const unsigned so = soff[j];
        for (unsigned i = t; i < c; i += 256) {
            if (__uint_as_float(vals[so + i]) > thr) ob[qp[i]] = 0.0f;
        }
    }
}

// ---- fb_exact: guaranteed-exact single-kernel fallback. One block per sample does a
//      full 3-level radix over ALL positives (re-reading f,g per sweep) then applies.
//      mode 1: predicated on fail (no-op in the common case). mode 2: unconditional. ----
__global__ __launch_bounds__(256) void fb_exact_kernel(const float4* __restrict__ f,
                                                       const float4* __restrict__ g,
                                                       float4* __restrict__ out,
                                                       const unsigned* __restrict__ fail,
                                                       int mode) {
    if (mode == 1 && fail[0] == 0u) return;
    const int b = blockIdx.x, t = threadIdx.x;
    __shared__ unsigned h[NB];
    __shared__ float sthr;
    const size_t base = (size_t)b * NPSV;
    // sweep 1: bits 30..18 over all positives
    for (int k = t; k < NB; k += 256) h[k] = 0u;
    __syncthreads();
    for (int i = t; i < NPSV; i += 256) {
        const float4 fv = f[base + i];
        const float4 gv = g[base + i];
#define H1(p) { if ((p) > 0.0f) atomicAdd(&h[__float_as_uint(p) >> 18], 1u); }
        H1(fv.x * gv.x) H1(fv.y * gv.y) H1(fv.z * gv.z) H1(fv.w * gv.w)
#undef H1
    }
    __syncthreads();
    unsigned P1, r1; select_in_lds<NB>(h, KSEL, &P1, &r1);
    __syncthreads();
    if (P1 == SENT) {                 // fewer than K positives: threshold 0 (exact)
        if (t == 0) sthr = 0.0f;
        __syncthreads();
    } else {
        // sweep 2: bits 17..5 within P1
        for (int k = t; k < NB; k += 256) h[k] = 0u;
        __syncthreads();
        for (int i = t; i < NPSV; i += 256) {
            const float4 fv = f[base + i];
            const float4 gv = g[base + i];
#define H2(p) { if ((p) > 0.0f) { const unsigned u = __float_as_uint(p); \
                if ((u >> 18) == P1) atomicAdd(&h[(u >> 5) & (NB - 1u)], 1u); } }
            H2(fv.x * gv.x) H2(fv.y * gv.y) H2(fv.z * gv.z) H2(fv.w * gv.w)
#undef H2
        }
        __syncthreads();
        unsigned P2, r2; select_in_lds<NB>(h, r1, &P2, &r2);
        __syncthreads();
        // sweep 3: bits 4..0 within (P1,P2)
        if (t < 32) h[t] = 0u;
        __syncthreads();
        const unsigned pref = (P1 << 13) | P2;
        for (int i = t; i < NPSV; i += 256) {
            const float4 fv = f[base + i];
            const float4 gv = g[base + i];
#define H3(p) { if ((p) > 0.0f) { const unsigned u = __float_as_uint(p); \
                if ((u >> 5) == pref) atomicAdd(&h[u & 31u], 1u); } }
            H3(fv.x * gv.x) H3(fv.y * gv.y) H3(fv.z * gv.z) H3(fv.w * gv.w)
#undef H3
        }
        __syncthreads();
        if (t == 0) {
            unsigned cur = 0, b3 = 0;
            for (int q = 31; q >= 0; --q) {
                const unsigned c = h[q];
                if (cur < r2 && cur + c >= r2) { b3 = (unsigned)q; break; }
                cur += c;
            }
            sthr = __uint_as_float((P1 << 18) | (P2 << 5) | b3);
        }
        __syncthreads();
    }
    // apply
    const float thr = sthr;
    for (int i = t; i < NPSV; i += 256) {
        const float4 fv = f[base + i];
        const float4 gv = g[base + i];
        float4 o;
        o.x = (fv.x * gv.x > thr) ? 0.0f : fv.x;
        o.y = (fv.y * gv.y > thr) ? 0.0f : fv.y;
        o.z = (fv.z * gv.z > thr) ? 0.0f : fv.z;
        o.w = (fv.w * gv.w > thr) ? 0.0f : fv.w;
        out[base + i] = o;
    }
}

extern "C" void kernel_launch(void* const* d_in, const int* in_sizes, int n_in,
                              void* d_out, int out_size, void* d_ws, size_t ws_size,
                              hipStream_t stream) {
    const float* f = (const float*)d_in[0];
    const float* g = (const float*)d_in[1];
    float* out = (float*)d_out;

    const size_t pairU32  = (size_t)NS * GX * PAIRCAP;                       // 2,097,152
    const size_t brBytes  = (size_t)NS * BRB * NB * sizeof(unsigned short);  // 8 MB
    const size_t bigBytes = (pairU32 * 8 > brBytes) ? pairU32 * 8 : brBytes; // 16.78 MB
    const size_t smallU32 = 2 * NS + NS * GX + NS * GX + 1 + NS;
    const size_t need     = bigBytes + smallU32 * 4;

    if (ws_size >= need) {
        // ---- tier-1 fast path: bracket hists and pairs share (time-disjoint) ws ----
        char* w = (char*)d_ws;
        unsigned short* bh = (unsigned short*)w;
        unsigned* pv   = (unsigned*)w;
        unsigned* ppos = pv + pairU32;
        unsigned* sm   = (unsigned*)(w + bigBytes);
        unsigned* binLU = sm;                  // 128
        unsigned* cnts  = binLU + 2 * NS;      // NS*GX
        unsigned* chis  = cnts + NS * GX;      // NS*GX
        unsigned* fail  = chis + NS * GX;      // 1
        float*    thrF  = (float*)(fail + 1);  // 64

        bracket_kernel<<<dim3(BRB, NS), 256, 0, stream>>>((const float4*)f, (const float4*)g,
                                                          bh, fail);
        bracket_scan_kernel<<<NS, 256, 0, stream>>>(bh, binLU);
        scatter0_kernel<<<dim3(GX, NS), 256, 0, stream>>>((const float4*)f, (const float4*)g,
                                                          (float4*)out, pv, ppos, binLU,
                                                          cnts, chis, fail);
        select0_kernel<<<NS, 256, 0, stream>>>(pv, ppos, binLU, cnts, chis, fail, thrF, out);
        // guaranteed-exact single-launch fallback; no-op unless fail was set
        fb_exact_kernel<<<NS, 256, 0, stream>>>((const float4*)f, (const float4*)g,
                                                (float4*)out, fail, 1);
    } else {
        // ---- tier-2: no usable ws; run the unconditional exact path (slow, correct) ----
        fb_exact_kernel<<<NS, 256, 0, stream>>>((const float4*)f, (const float4*)g,
                                                (float4*)out, (const unsigned*)d_out, 2);
    }
}

// Round 15
// 212.603 us; speedup vs baseline: 1.1135x; 1.1135x over previous
//
#include <hip/hip_runtime.h>

namespace {
constexpr int NS   = 64;                 // batch
constexpr int NPS  = 802816;             // elements per sample (256*56*56)
constexpr int NPSV = NPS / 4;            // float4 per sample (200704)
constexpr unsigned KSEL = 80281u;        // int(0.1 * 802816)
constexpr unsigned SENT = 0xFFFFFFFFu;
constexpr int NB   = 8192;               // 13-bit prefix bins (u >> 18)
constexpr int GX   = 16;                 // scatter blocks per sample (interleaved tiles)
constexpr int TPB  = 49;                 // tiles per scatter block (784 = 16*49, no tail)
constexpr int PAIRCAP = 2048;            // candidate capacity per scatter block
constexpr int CAP_LDS = 20480;           // per-sample candidate cap for LDS select
constexpr int BRB  = 8;                  // bracket blocks per sample
constexpr int CHUNKS = 128;              // sampled 256-float4 chunks per sample
constexpr int CH_STRIDE = NPSV / CHUNKS; // 1568 float4 between chunk starts
// sample M = 131072 elems; mean rank of k-th = 13109, sigma = 108.6; +/-9 sigma
constexpr unsigned RU_RANK = 12129u;
constexpr unsigned RL_RANK = 14086u;
typedef float f32x4 __attribute__((ext_vector_type(4)));
}

// non-temporal 16B store: keeps the out-stream from evicting f/g in L2/L3
// (graph replays re-read f/g; nt preserved ~219 µs totals vs 236 with plain stores)
__device__ __forceinline__ void nt_store4(float4* dst, const float4& v) {
    f32x4 w; w.x = v.x; w.y = v.y; w.z = v.z; w.w = v.w;
    __builtin_nontemporal_store(w, reinterpret_cast<f32x4*>(dst));
}

// Find bin B (descending) with suffix(B) < K <= suffix(B)+h[B]. SENT if total < K.
// Results are register-latched before the final barrier so back-to-back calls are safe.
template <int NBINS>
__device__ void select_in_lds(const unsigned* __restrict__ h, unsigned K,
                              unsigned* bin, unsigned* rem) {
    constexpr int BPT = NBINS / 256;
    __shared__ unsigned cs[256];
    __shared__ unsigned fB, fR;
    const int t = threadIdx.x;
    unsigned s = 0;
    for (int j = 0; j < BPT; ++j) s += h[t * BPT + j];
    cs[t] = s;
    if (t == 0) { fB = SENT; fR = 0u; }
    __syncthreads();
    unsigned suf = 0;
    for (int j = t + 1; j < 256; ++j) suf += cs[j];
    if (suf < K && suf + s >= K) {
        unsigned cur = suf;
        for (int j = BPT - 1; j >= 0; --j) {
            const unsigned c = h[t * BPT + j];
            if (cur < K && cur + c >= K) { fB = (unsigned)(t * BPT + j); fR = K - cur; break; }
            cur += c;
        }
    }
    __syncthreads();
    const unsigned rb = fB, rr = fR;
    __syncthreads();
    *bin = rb; *rem = rr;
}

// ---- bracket: chunk-sampled 13-bit histogram, 8 blocks/sample -> u16 partials ----
__global__ __launch_bounds__(256) void bracket_kernel(const float4* __restrict__ f,
                                                      const float4* __restrict__ g,
                                                      unsigned short* __restrict__ bh,
                                                      unsigned* __restrict__ fail) {
    __shared__ unsigned h[NB];
    const int jb = blockIdx.x, b = blockIdx.y, t = threadIdx.x;
    if (jb == 0 && b == 0 && t == 0) fail[0] = 0u;
    for (int k = t; k < NB; k += 256) h[k] = 0u;
    __syncthreads();
    const size_t base = (size_t)b * NPSV;
#define HBIN(p) { if ((p) > 0.0f) atomicAdd(&h[__float_as_uint(p) >> 18], 1u); }
    for (int c = 0; c < CHUNKS / BRB; c += 2) {          // 2-chunk unroll: 4 loads in flight
        const int ch = jb * (CHUNKS / BRB) + c;
        const size_t i0 = base + (size_t)ch * CH_STRIDE + t;
        const size_t i1 = base + (size_t)(ch + 1) * CH_STRIDE + t;
        const float4 fa = f[i0], fb = f[i1];
        const float4 ga = g[i0], gb = g[i1];
        HBIN(fa.x * ga.x) HBIN(fa.y * ga.y) HBIN(fa.z * ga.z) HBIN(fa.w * ga.w)
        HBIN(fb.x * gb.x) HBIN(fb.y * gb.y) HBIN(fb.z * gb.z) HBIN(fb.w * gb.w)
    }
#undef HBIN
    __syncthreads();
    unsigned short* o = bh + (size_t)(b * BRB + jb) * NB;
    for (int k = t; k < NB; k += 256) o[k] = (unsigned short)h[k];  // <=16384, fits u16
}

// ---- bracket_scan: dense uint4 reads — thread owns 8 consecutive bins, no atomics ----
__global__ __launch_bounds__(256) void bracket_scan_kernel(const unsigned short* __restrict__ bh,
                                                           unsigned* __restrict__ binLU) {
    __shared__ unsigned h[NB];
    const int b = blockIdx.x, t = threadIdx.x;
    for (int grp = t; grp < NB / 8; grp += 256) {        // 4 iterations
        unsigned acc[8] = {0, 0, 0, 0, 0, 0, 0, 0};
        for (int j = 0; j < BRB; ++j) {
            const uint4 v = *reinterpret_cast<const uint4*>(
                bh + (size_t)(b * BRB + j) * NB + grp * 8);   // 8 contiguous u16
            acc[0] += v.x & 0xFFFFu; acc[1] += v.x >> 16;
            acc[2] += v.y & 0xFFFFu; acc[3] += v.y >> 16;
            acc[4] += v.z & 0xFFFFu; acc[5] += v.z >> 16;
            acc[6] += v.w & 0xFFFFu; acc[7] += v.w >> 16;
        }
        for (int e = 0; e < 8; ++e) h[grp * 8 + e] = acc[e];
    }
    __syncthreads();
    unsigned bU, rU, bL, rL;
    select_in_lds<NB>(h, RU_RANK, &bU, &rU);
    select_in_lds<NB>(h, RL_RANK, &bL, &rL);
    if (t == 0) {
        binLU[2 * b]     = (bL == SENT) ? 0u : bL;
        binLU[2 * b + 1] = (bU == SENT) ? (unsigned)(NB - 1) : bU;
    }
}

// ---- scatter0: interleaved tile mapping, nt stores; candidate appends staged
//      in LDS, flushed coalesced at block end ----
__global__ __launch_bounds__(256) void scatter0_kernel(const float4* __restrict__ f,
                                                       const float4* __restrict__ g,
                                                       float4* __restrict__ out,
                                                       unsigned* __restrict__ pv,
                                                       unsigned* __restrict__ ppos,
                                                       const unsigned* __restrict__ binLU,
                                                       unsigned* __restrict__ cnts,
                                                       unsigned* __restrict__ chis,
                                                       unsigned* __restrict__ fail) {
    const int j = blockIdx.x, b = blockIdx.y, t = threadIdx.x;
    const unsigned binL = binLU[2 * b], binU = binLU[2 * b + 1];
    __shared__ unsigned cnt;
    __shared__ unsigned wsum[4];
    __shared__ unsigned lv[PAIRCAP];
    __shared__ unsigned lp[PAIRCAP];
    if (t == 0) cnt = 0u;
    __syncthreads();
    const size_t sbase = (size_t)b * NPSV;
    unsigned chi = 0;
#define PROC(FC, GC, IDX, CIDX, OC) { \
        const float p_ = (FC) * (GC); \
        const unsigned u_ = __float_as_uint(p_); \
        const unsigned pre_ = u_ >> 18; \
        const bool pos_ = p_ > 0.0f; \
        const bool drop_ = pos_ && (pre_ > binU); \
        OC = drop_ ? 0.0f : (FC); \
        chi += drop_; \
        if (pos_ && pre_ >= binL && pre_ <= binU) { \
            const unsigned x_ = atomicAdd(&cnt, 1u); \
            if (x_ < PAIRCAP) { lv[x_] = u_; lp[x_] = (unsigned)((IDX) * 4) + CIDX; } \
        } }
#define PROC4(FV, GV, IDX, OV) \
        PROC(FV.x, GV.x, IDX, 0u, OV.x) PROC(FV.y, GV.y, IDX, 1u, OV.y) \
        PROC(FV.z, GV.z, IDX, 2u, OV.z) PROC(FV.w, GV.w, IDX, 3u, OV.w)

    for (int k = 0; k < TPB; ++k) {
        const int i = (k * GX + j) * 256 + t;    // f4 index within sample
        const float4 fv = f[sbase + i];
        const float4 gv = g[sbase + i];
        float4 o;
        PROC4(fv, gv, i, o)
        nt_store4(&out[sbase + i], o);
    }
#undef PROC4
#undef PROC
    // block-reduce chi
    for (int off = 32; off; off >>= 1) chi += __shfl_down(chi, off);
    if ((t & 63) == 0) wsum[t >> 6] = chi;
    __syncthreads();
    // coalesced flush of the candidate staging
    const unsigned ctot = cnt;
    const unsigned c = (ctot > PAIRCAP) ? PAIRCAP : ctot;
    const size_t segp = (size_t)(b * GX + j) * PAIRCAP;
    for (unsigned k = t; k < c; k += 256) { pv[segp + k] = lv[k]; ppos[segp + k] = lp[k]; }
    if (t == 0) {
        chis[b * GX + j] = wsum[0] + wsum[1] + wsum[2] + wsum[3];
        cnts[b * GX + j] = c;
        if (ctot > PAIRCAP) fail[0] = 1u;   // overflow -> exact fallback
    }
}

// ---- select0+fixup: LDS-resident exact 3-level radix select, then zero the
//      candidate positions above the threshold (vals already in LDS) ----
__global__ __launch_bounds__(256) void select0_kernel(const unsigned* __restrict__ pv,
                                                      const unsigned* __restrict__ ppos,
                                                      const unsigned* __restrict__ binLU,
                                                      const unsigned* __restrict__ cnts,
                                                      const unsigned* __restrict__ chis,
                                                      unsigned* __restrict__ fail,
                                                      float* __restrict__ thrF,
                                                      float* __restrict__ out) {
    if (fail[0]) return;
    const int b = blockIdx.x, t = threadIdx.x;
    __shared__ unsigned vals[CAP_LDS];
    __shared__ unsigned hist[NB];
    __shared__ unsigned soff[GX + 1];
    __shared__ unsigned sh_chi;
    __shared__ float sh_thr;
    if (t == 0) {
        unsigned o = 0;
        for (int j = 0; j < GX; ++j) { soff[j] = o; o += cnts[b * GX + j]; }
        soff[GX] = o;
        unsigned c = 0;
        for (int j = 0; j < GX; ++j) c += chis[b * GX + j];
        sh_chi = c;
    }
    __syncthreads();
    const unsigned ncand = soff[GX];
    const unsigned chi = sh_chi;
    if (chi >= KSEL) { if (t == 0) fail[0] = 1u; return; }      // k-th above bracket
    if (ncand > CAP_LDS) { if (t == 0) fail[0] = 1u; return; }
    const unsigned Krem = KSEL - chi;
    bool zeroThr = false;
    if (Krem > ncand) {
        if (binLU[2 * b] == 0u) zeroThr = true;                 // < k positives: thr = 0
        else { if (t == 0) fail[0] = 1u; return; }              // k-th below bracket
    }
    // load candidates into LDS
    for (int j = 0; j < GX; ++j) {
        const unsigned c = soff[j + 1] - soff[j];
        const unsigned* s = pv + (size_t)(b * GX + j) * PAIRCAP;
        for (unsigned i = t; i < c; i += 256) vals[soff[j] + i] = s[i];
    }
    if (zeroThr) {
        if (t == 0) { sh_thr = 0.0f; thrF[b] = 0.0f; }
        __syncthreads();
    } else {
        // sweep 1: bits 30..18
        for (int k = t; k < NB; k += 256) hist[k] = 0u;
        __syncthreads();
        for (unsigned i = t; i < ncand; i += 256) atomicAdd(&hist[vals[i] >> 18], 1u);
        __syncthreads();
        unsigned P1, r1; select_in_lds<NB>(hist, Krem, &P1, &r1);
        __syncthreads();
        // sweep 2: bits 17..5
        for (int k = t; k < NB; k += 256) hist[k] = 0u;
        __syncthreads();
        for (unsigned i = t; i < ncand; i += 256) {
            const unsigned u = vals[i];
            if ((u >> 18) == P1) atomicAdd(&hist[(u >> 5) & (NB - 1u)], 1u);
        }
        __syncthreads();
        unsigned P2, r2; select_in_lds<NB>(hist, r1, &P2, &r2);
        __syncthreads();
        // sweep 3: bits 4..0
        if (t < 32) hist[t] = 0u;
        __syncthreads();
        const unsigned pref = (P1 << 13) | P2;
        for (unsigned i = t; i < ncand; i += 256) {
            const unsigned u = vals[i];
            if ((u >> 5) == pref) atomicAdd(&hist[u & 31u], 1u);
        }
        __syncthreads();
        if (t == 0) {
            unsigned cur = 0, b3 = 0;
            for (int q = 31; q >= 0; --q) {
                const unsigned c = hist[q];
                if (cur < r2 && cur + c >= r2) { b3 = (unsigned)q; break; }
                cur += c;
            }
            const float thr = __uint_as_float((P1 << 18) | (P2 << 5) | b3);
            sh_thr = thr; thrF[b] = thr;
        }
        __syncthreads();
    }
    // fixup: zero candidate positions whose value exceeds thr
    const float thr = sh_thr;
    float* ob = out + (size_t)b * NPS;
    for (int j = 0; j < GX; ++j) {
        const unsigned c = soff[j + 1] - soff[j];
        const unsigned* qp = ppos + (size_t)(b * GX + j) * PAIRCAP;
        const unsigned so = soff[j];
        for (unsigned i = t; i < c; i += 256) {
            if (__uint_as_float(vals[so + i]) > thr) ob[qp[i]] = 0.0f;
        }
    }
}

// ---- fb_exact: guaranteed-exact single-kernel fallback. One block per sample does a
//      full 3-level radix over ALL positives (re-reading f,g per sweep) then applies.
//      mode 1: predicated on fail (no-op in the common case). mode 2: unconditional. ----
__global__ __launch_bounds__(256) void fb_exact_kernel(const float4* __restrict__ f,
                                                       const float4* __restrict__ g,
                                                       float4* __restrict__ out,
                                                       const unsigned* __restrict__ fail,
                                                       int mode) {
    if (mode == 1 && fail[0] == 0u) return;
    const int b = blockIdx.x, t = threadIdx.x;
    __shared__ unsigned h[NB];
    __shared__ float sthr;
    const size_t base = (size_t)b * NPSV;
    // sweep 1: bits 30..18 over all positives
    for (int k = t; k < NB; k += 256) h[k] = 0u;
    __syncthreads();
    for (int i = t; i < NPSV; i += 256) {
        const float4 fv = f[base + i];
        const float4 gv = g[base + i];
#define H1(p) { if ((p) > 0.0f) atomicAdd(&h[__float_as_uint(p) >> 18], 1u); }
        H1(fv.x * gv.x) H1(fv.y * gv.y) H1(fv.z * gv.z) H1(fv.w * gv.w)
#undef H1
    }
    __syncthreads();
    unsigned P1, r1; select_in_lds<NB>(h, KSEL, &P1, &r1);
    __syncthreads();
    if (P1 == SENT) {                 // fewer than K positives: threshold 0 (exact)
        if (t == 0) sthr = 0.0f;
        __syncthreads();
    } else {
        // sweep 2: bits 17..5 within P1
        for (int k = t; k < NB; k += 256) h[k] = 0u;
        __syncthreads();
        for (int i = t; i < NPSV; i += 256) {
            const float4 fv = f[base + i];
            const float4 gv = g[base + i];
#define H2(p) { if ((p) > 0.0f) { const unsigned u = __float_as_uint(p); \
                if ((u >> 18) == P1) atomicAdd(&h[(u >> 5) & (NB - 1u)], 1u); } }
            H2(fv.x * gv.x) H2(fv.y * gv.y) H2(fv.z * gv.z) H2(fv.w * gv.w)
#undef H2
        }
        __syncthreads();
        unsigned P2, r2; select_in_lds<NB>(h, r1, &P2, &r2);
        __syncthreads();
        // sweep 3: bits 4..0 within (P1,P2)
        if (t < 32) h[t] = 0u;
        __syncthreads();
        const unsigned pref = (P1 << 13) | P2;
        for (int i = t; i < NPSV; i += 256) {
            const float4 fv = f[base + i];
            const float4 gv = g[base + i];
#define H3(p) { if ((p) > 0.0f) { const unsigned u = __float_as_uint(p); \
                if ((u >> 5) == pref) atomicAdd(&h[u & 31u], 1u); } }
            H3(fv.x * gv.x) H3(fv.y * gv.y) H3(fv.z * gv.z) H3(fv.w * gv.w)
#undef H3
        }
        __syncthreads();
        if (t == 0) {
            unsigned cur = 0, b3 = 0;
            for (int q = 31; q >= 0; --q) {
                const unsigned c = h[q];
                if (cur < r2 && cur + c >= r2) { b3 = (unsigned)q; break; }
                cur += c;
            }
            sthr = __uint_as_float((P1 << 18) | (P2 << 5) | b3);
        }
        __syncthreads();
    }
    // apply
    const float thr = sthr;
    for (int i = t; i < NPSV; i += 256) {
        const float4 fv = f[base + i];
        const float4 gv = g[base + i];
        float4 o;
        o.x = (fv.x * gv.x > thr) ? 0.0f : fv.x;
        o.y = (fv.y * gv.y > thr) ? 0.0f : fv.y;
        o.z = (fv.z * gv.z > thr) ? 0.0f : fv.z;
        o.w = (fv.w * gv.w > thr) ? 0.0f : fv.w;
        out[base + i] = o;
    }
}

extern "C" void kernel_launch(void* const* d_in, const int* in_sizes, int n_in,
                              void* d_out, int out_size, void* d_ws, size_t ws_size,
                              hipStream_t stream) {
    const float* f = (const float*)d_in[0];
    const float* g = (const float*)d_in[1];
    float* out = (float*)d_out;

    const size_t pairU32  = (size_t)NS * GX * PAIRCAP;                       // 2,097,152
    const size_t brBytes  = (size_t)NS * BRB * NB * sizeof(unsigned short);  // 8 MB
    const size_t bigBytes = (pairU32 * 8 > brBytes) ? pairU32 * 8 : brBytes; // 16.78 MB
    const size_t smallU32 = 2 * NS + NS * GX + NS * GX + 1 + NS;
    const size_t need     = bigBytes + smallU32 * 4;

    if (ws_size >= need) {
        // ---- tier-1 fast path: bracket hists and pairs share (time-disjoint) ws ----
        char* w = (char*)d_ws;
        unsigned short* bh = (unsigned short*)w;
        unsigned* pv   = (unsigned*)w;
        unsigned* ppos = pv + pairU32;
        unsigned* sm   = (unsigned*)(w + bigBytes);
        unsigned* binLU = sm;                  // 128
        unsigned* cnts  = binLU + 2 * NS;      // NS*GX
        unsigned* chis  = cnts + NS * GX;      // NS*GX
        unsigned* fail  = chis + NS * GX;      // 1
        float*    thrF  = (float*)(fail + 1);  // 64

        bracket_kernel<<<dim3(BRB, NS), 256, 0, stream>>>((const float4*)f, (const float4*)g,
                                                          bh, fail);
        bracket_scan_kernel<<<NS, 256, 0, stream>>>(bh, binLU);
        scatter0_kernel<<<dim3(GX, NS), 256, 0, stream>>>((const float4*)f, (const float4*)g,
                                                          (float4*)out, pv, ppos, binLU,
                                                          cnts, chis, fail);
        select0_kernel<<<NS, 256, 0, stream>>>(pv, ppos, binLU, cnts, chis, fail, thrF, out);
        // guaranteed-exact single-launch fallback; no-op unless fail was set
        fb_exact_kernel<<<NS, 256, 0, stream>>>((const float4*)f, (const float4*)g,
                                                (float4*)out, fail, 1);
    } else {
        // ---- tier-2: no usable ws; run the unconditional exact path (slow, correct) ----
        fb_exact_kernel<<<NS, 256, 0, stream>>>((const float4*)f, (const float4*)g,
                                                (float4*)out, (const unsigned*)d_out, 2);
    }
}